// Round 11
// baseline (98.950 us; speedup 1.0000x reference)
//
#include <hip/hip_runtime.h>
#include <hip/hip_bf16.h>

#define H 768
#define SEQ 256
#define NPAIR 32896                // S*(S+1)/2 = 128*257
#define NTOT 131584                // 4*NPAIR = 1028*128
#define NOUTP 160
#define OFF_H2H 263168u            // 4*32896*2
#define OFF_T2T 9737216u           // OFF_H2H + 4*24*32896*3

#define N_BPK 122880               // 12 chunks * 20 frags * 64 lanes * 8 bf16 (real slots)
#define N_FCW 1179648              // 1536*768
#define SCL 2.8853900817779268f    // 2*log2(e): pre-scale L/R so stage tanh needs no mul

#define CH 64                      // k-elems per chunk
#define NCH 12
#define BSLOT 24576                // padded B chunk bytes (real 20480)
#define SLAB_STR 166               // bf16 slab stride (83 words, odd -> conflict-free)

typedef short bf16x8 __attribute__((ext_vector_type(8)));
typedef float f32x4 __attribute__((ext_vector_type(4)));

__device__ __forceinline__ float tanh_s(float xs) {
    // xs = 2*log2(e)*x  ->  tanh(x) = 1 - 2/(exp2(xs)+1)
    float e = __builtin_amdgcn_exp2f(xs);
    return fmaf(-2.0f, __builtin_amdgcn_rcpf(e + 1.0f), 1.0f);
}
__device__ __forceinline__ float bf_lo(int w){ return __uint_as_float(((unsigned)w) << 16); }
__device__ __forceinline__ float bf_hi(int w){ return __uint_as_float(((unsigned)w) & 0xffff0000u); }
__device__ __forceinline__ float bfu(unsigned short u){ return __uint_as_float(((unsigned)u) << 16); }
__device__ __forceinline__ int cvtpk(float lo, float hi) {
    int r;
    asm("v_cvt_pk_bf16_f32 %0, %1, %2" : "=v"(r) : "v"(lo), "v"(hi));
    return r;
}
__device__ __forceinline__ unsigned short bf16r(float x){
    unsigned int u = __float_as_uint(x);
    u += 0x7fffu + ((u >> 16) & 1u);
    return (unsigned short)(u >> 16);
}
__device__ __forceinline__ bf16x8 tanh_frag(int4 lv, int4 rv) {
    int4 st;
    st.x = cvtpk(tanh_s(bf_lo(lv.x) + bf_lo(rv.x)), tanh_s(bf_hi(lv.x) + bf_hi(rv.x)));
    st.y = cvtpk(tanh_s(bf_lo(lv.y) + bf_lo(rv.y)), tanh_s(bf_hi(lv.y) + bf_hi(rv.y)));
    st.z = cvtpk(tanh_s(bf_lo(lv.z) + bf_lo(rv.z)), tanh_s(bf_hi(lv.z) + bf_hi(rv.z)));
    st.w = cvtpk(tanh_s(bf_lo(lv.w) + bf_lo(rv.w)), tanh_s(bf_hi(lv.w) + bf_hi(rv.w)));
    return __builtin_bit_cast(bf16x8, st);
}

typedef const __attribute__((address_space(1))) unsigned int* as1_u32p;
typedef __attribute__((address_space(3))) unsigned int* as3_u32p;
__device__ __forceinline__ void gload_lds16(const void* g, void* l) {
    __builtin_amdgcn_global_load_lds((as1_u32p)g, (as3_u32p)l, 16, 0, 0);
}

__device__ __forceinline__ int row_start(int i) { return i * SEQ - (i * (i - 1)) / 2; }
__device__ __forceinline__ void pair_ij(int p, int& oi, int& oj) {
    double disc = 263169.0 - 8.0 * (double)p;   // (2S+1)^2 - 8p
    int i = (int)((513.0 - sqrt(disc)) * 0.5);
    if (i > 0 && row_start(i) > p) --i;
    while (row_start(i + 1) <= p) ++i;
    oi = i;
    oj = i + (p - row_start(i));
}
__device__ __forceinline__ int batch_of(int g) {
    return (g >= 3 * NPAIR) ? 3 : (g >= 2 * NPAIR) ? 2 : (g >= NPAIR) ? 1 : 0;
}

// ---------------- kernel 0: pack Bpk (CH=64 fragment order, 24KB-strided chunks), fcwb, bc ----------------
// chunk c, frag = kk*10+f, lane, j ->  W[n = f*16+(lane&15)][k = c*64 + kk*32 + (lane>>4)*8 + j]
__global__ __launch_bounds__(256) void pack_kernel(
    const float* __restrict__ h2t_w, const float* __restrict__ h2h_w,
    const float* __restrict__ t2t_w, const float* __restrict__ h2t_b,
    const float* __restrict__ h2h_b, const float* __restrict__ t2t_b,
    const float* __restrict__ fc_w,
    unsigned short* __restrict__ Bpk, unsigned short* __restrict__ fcwb,
    float* __restrict__ bc)
{
    int idx = blockIdx.x * 256 + threadIdx.x;
    if (idx < N_BPK) {
        int j = idx & 7, lane = (idx >> 3) & 63, rest = idx >> 9;
        int frag = rest % 20, c = rest / 20;
        int f = frag % 10, kk = frag / 10;
        int n = f * 16 + (lane & 15);
        int k = c * CH + kk * 32 + ((lane >> 4) << 3) + j;
        float v = 0.f;
        if (n < 2)        v = h2t_w[n * H + k];
        else if (n < 74)  v = h2h_w[(n - 2) * H + k];
        else if (n < 146) v = t2t_w[(n - 74) * H + k];
        Bpk[c * 12288 + (idx - c * 10240)] = bf16r(v);   // 12288 shorts = 24576 B stride
    } else if (idx < N_BPK + N_FCW) {
        int q = idx - N_BPK;
        int n = q / H, k = q % H;
        float v = (n < H) ? fc_w[(size_t)n * 2 * H + k]
                          : fc_w[(size_t)(n - H) * 2 * H + H + k];
        fcwb[q] = bf16r(v);
    } else if (idx < N_BPK + N_FCW + NOUTP) {
        int q = idx - N_BPK - N_FCW;
        float v = 0.f;
        if (q < 2)        v = h2t_b[q];
        else if (q < 74)  v = h2h_b[q - 2];
        else if (q < 146) v = t2t_b[q - 74];
        bc[q] = v;
    }
}

// ---------------- kernel 1: LB/RB = hidden @ fc_w (bf16 MFMA GEMM, 64x64 tiles), pre-scaled ----------------
__global__ __launch_bounds__(256, 2) void lr_mfma(
    const float* __restrict__ hidden, const unsigned short* __restrict__ fcwb,
    const float* __restrict__ fc_b,
    unsigned short* __restrict__ LB, unsigned short* __restrict__ RB)
{
    __shared__ __align__(16) char sm[16384];          // A 8KB | B 8KB
    const int tid = threadIdx.x, l = tid & 63, w = tid >> 6;
    const int wm = w >> 1, wn = w & 1;
    const int m0 = blockIdx.x * 64, n0 = blockIdx.y * 64;
    f32x4 acc[2][2] = {};
    for (int c = 0; c < 12; ++c) {
        const int k0 = c * 64;
        #pragma unroll
        for (int it = 0; it < 2; ++it) {              // A: 64 rows x 64 k, cvt f32->bf16
            int idx = tid + it * 256;
            int row = idx >> 3, k8 = idx & 7;
            const float4* src = reinterpret_cast<const float4*>(hidden + (size_t)(m0 + row) * H + k0 + k8 * 8);
            float4 a = src[0], bq = src[1];
            int4 st;
            st.x = cvtpk(a.x, a.y);  st.y = cvtpk(a.z, a.w);
            st.z = cvtpk(bq.x, bq.y); st.w = cvtpk(bq.z, bq.w);
            *reinterpret_cast<int4*>(sm + row * 128 + ((k8 * 16) ^ ((row & 7) << 4))) = st;
        }
        #pragma unroll
        for (int it = 0; it < 2; ++it) {              // B: 64 rows x 64 k
            int idx = tid + it * 256;
            int row = idx >> 3, k8 = idx & 7;
            *reinterpret_cast<int4*>(sm + 8192 + row * 128 + ((k8 * 16) ^ ((row & 7) << 4))) =
                *reinterpret_cast<const int4*>(fcwb + (size_t)(n0 + row) * H + k0 + k8 * 8);
        }
        __syncthreads();
        #pragma unroll
        for (int kk = 0; kk < 2; ++kk) {
            const int sl = kk * 4 + (l >> 4);
            const int swz = (l & 7) << 4;
            bf16x8 af[2], bfr[2];
            #pragma unroll
            for (int a = 0; a < 2; ++a) {
                int row = 32 * wm + 16 * a + (l & 15);
                af[a] = *reinterpret_cast<const bf16x8*>(sm + row * 128 + ((sl * 16) ^ swz));
            }
            #pragma unroll
            for (int f = 0; f < 2; ++f) {
                int row = 32 * wn + 16 * f + (l & 15);
                bfr[f] = *reinterpret_cast<const bf16x8*>(sm + 8192 + row * 128 + ((sl * 16) ^ swz));
            }
            #pragma unroll
            for (int a = 0; a < 2; ++a)
                #pragma unroll
                for (int f = 0; f < 2; ++f)
                    acc[a][f] = __builtin_amdgcn_mfma_f32_16x16x32_bf16(af[a], bfr[f], acc[a][f], 0, 0, 0);
        }
        __syncthreads();
    }
    #pragma unroll
    for (int a = 0; a < 2; ++a)
        #pragma unroll
        for (int f = 0; f < 2; ++f)
            #pragma unroll
            for (int r = 0; r < 4; ++r) {
                int row = m0 + 32 * wm + 16 * a + 4 * (l >> 4) + r;
                int col = n0 + 32 * wn + 16 * f + (l & 15);
                float v = acc[a][f][r];
                if (n0 < H) LB[(size_t)row * H + col] = bf16r((v + fc_b[col]) * SCL);
                else        RB[(size_t)row * H + (col - H)] = bf16r(v * SCL);
            }
}

// ---------------- kernel 2: M=128, 8-wave, CH=64, 12 counted-vmcnt barriers ----------------
// block = 512 thr (8 waves x 16 rows), wave cols = 160 (acc[10] = 40 regs), grid = 1028 (exact).
// A: tanh straight into frags (2 frags/thread/chunk). B: 3 uniform gload_lds/thread into 24KB dbuf half.
__global__ __launch_bounds__(512, 2) void pair_mfma(
    const unsigned short* __restrict__ LB, const unsigned short* __restrict__ RB,
    const unsigned short* __restrict__ Bpk, const float* __restrict__ bc,
    float* __restrict__ out)
{
    __shared__ __align__(16) char sm[49792];
    // K-loop: B buf0 [0,24576) | buf1 [24576,49152)
    // epilogue: bf16 slab [128][166] = 42496 B at [0,42496)
    // bc_s [49152,49792) lives throughout
    float* bc_s = reinterpret_cast<float*>(sm + 49152);

    const int tid = threadIdx.x, l = tid & 63, w = tid >> 6;
    const int g0 = blockIdx.x * 128;                 // tile base; NPAIR % 128 == 0 -> no batch straddle
    const int b = batch_of(g0);
    const int p0 = g0 - b * NPAIR;

    if (tid < NOUTP) bc_s[tid] = bc[tid];

    // per-thread pair decode (4 threads per row redundantly; no LDS staging)
    const int row = 16 * w + (l & 15);
    int pi, pj;
    pair_ij(p0 + row, pi, pj);
    const int kb = (l >> 4) << 3;                    // lane k-seg base (bf16 units)
    const unsigned short* lp = LB + (size_t)(b * SEQ + pi) * H + kb;
    const unsigned short* rp = RB + (size_t)(b * SEQ + pj) * H + kb;

    // B staging: 3 uniform rounds of 8 KB (512 thr x 16 B); per-lane src, wave-uniform dest
    const char* bpk = reinterpret_cast<const char*>(Bpk);
    const int soff = tid * 16;                       // = w*1024 + l*16
    const int doff = w * 1024;

    f32x4 acc[10] = {};

    {   // prologue: B(0) -> buf0 ; LR(0) -> regs
        gload_lds16(bpk + soff,          sm + doff);
        gload_lds16(bpk + soff + 8192,   sm + doff + 8192);
        gload_lds16(bpk + soff + 16384,  sm + doff + 16384);
        __builtin_amdgcn_sched_barrier(0);
    }
    int4 lv0 = *reinterpret_cast<const int4*>(lp);
    int4 lv1 = *reinterpret_cast<const int4*>(lp + 32);
    int4 rv0 = *reinterpret_cast<const int4*>(rp);
    int4 rv1 = *reinterpret_cast<const int4*>(rp + 32);
    asm volatile("s_waitcnt vmcnt(4) lgkmcnt(0)" ::: "memory");   // drain B(0); keep 4 LR in flight
    __builtin_amdgcn_s_barrier();
    __builtin_amdgcn_sched_barrier(0);

    #pragma unroll 2
    for (int c = 0; c < NCH - 1; ++c) {
        char* bufn = sm + (((c + 1) & 1) ? BSLOT : 0);
        const char* bn = bpk + (c + 1) * BSLOT + soff;
        // phase 1: B(c+1) -> bufn (oldest after this chunk's LR issue)
        gload_lds16(bn,          bufn + doff);
        gload_lds16(bn + 8192,   bufn + doff + 8192);
        gload_lds16(bn + 16384,  bufn + doff + 16384);
        __builtin_amdgcn_sched_barrier(0);
        // phase 2: tanh chunk c -> 2 A-frags (auto-vmcnt drains only the 4 LR, keeps B)
        bf16x8 a0 = tanh_frag(lv0, rv0);
        bf16x8 a1 = tanh_frag(lv1, rv1);
        // phase 3: issue LR(c+1) (newest: survive this chunk's counted barrier)
        const int co = (c + 1) * CH;
        lv0 = *reinterpret_cast<const int4*>(lp + co);
        lv1 = *reinterpret_cast<const int4*>(lp + co + 32);
        rv0 = *reinterpret_cast<const int4*>(rp + co);
        rv1 = *reinterpret_cast<const int4*>(rp + co + 32);
        // phase 4: 20 x {ds_read_b128 + MFMA} on bufc
        const char* bufc = sm + ((c & 1) ? BSLOT : 0);
        #pragma unroll
        for (int f = 0; f < 10; ++f) {
            bf16x8 bfr = *reinterpret_cast<const bf16x8*>(bufc + (f * 64 + l) * 16);
            acc[f] = __builtin_amdgcn_mfma_f32_16x16x32_bf16(a0, bfr, acc[f], 0, 0, 0);
        }
        #pragma unroll
        for (int f = 0; f < 10; ++f) {
            bf16x8 bfr = *reinterpret_cast<const bf16x8*>(bufc + ((10 + f) * 64 + l) * 16);
            acc[f] = __builtin_amdgcn_mfma_f32_16x16x32_bf16(a1, bfr, acc[f], 0, 0, 0);
        }
        // phase 5: counted barrier — drain B(c+1) (3), keep the 4 LR(c+1) in flight
        asm volatile("s_waitcnt vmcnt(4) lgkmcnt(0)" ::: "memory");
        __builtin_amdgcn_s_barrier();
        __builtin_amdgcn_sched_barrier(0);
    }
    {   // peeled chunk 11 (no prefetch); buf1 (11 odd)
        bf16x8 a0 = tanh_frag(lv0, rv0);
        bf16x8 a1 = tanh_frag(lv1, rv1);
        const char* bufc = sm + BSLOT;
        #pragma unroll
        for (int f = 0; f < 10; ++f) {
            bf16x8 bfr = *reinterpret_cast<const bf16x8*>(bufc + (f * 64 + l) * 16);
            acc[f] = __builtin_amdgcn_mfma_f32_16x16x32_bf16(a0, bfr, acc[f], 0, 0, 0);
        }
        #pragma unroll
        for (int f = 0; f < 10; ++f) {
            bf16x8 bfr = *reinterpret_cast<const bf16x8*>(bufc + ((10 + f) * 64 + l) * 16);
            acc[f] = __builtin_amdgcn_mfma_f32_16x16x32_bf16(a1, bfr, acc[f], 0, 0, 0);
        }
    }
    asm volatile("s_waitcnt lgkmcnt(0)" ::: "memory");   // all LDS reads retired before slab aliases
    __builtin_amdgcn_s_barrier();

    // epilogue: 8 waves dump 128 rows -> slab, one barrier, parallel softmax
    unsigned short* slab = reinterpret_cast<unsigned short*>(sm);
    #pragma unroll
    for (int f = 0; f < 10; ++f)
        #pragma unroll
        for (int r = 0; r < 4; ++r) {
            int rw = 16 * w + 4 * (l >> 4) + r;
            slab[rw * SLAB_STR + f * 16 + (l & 15)] = bf16r(acc[f][r]);
        }
    __syncthreads();

    if (tid < 256) {                                 // h2t: 128 rows x 2 (flat out idx = 2g+tt)
        int pr = tid >> 1, tt = tid & 1;
        float val = bfu(slab[pr * SLAB_STR + tt]) + bc_s[tt];
        __builtin_nontemporal_store(val, &out[(size_t)(g0 + pr) * 2 + tt]);
    }
    #pragma unroll
    for (int it = 0; it < 12; ++it) {                // 48 rr x 128 rows, rr-major (coalesced stores)
        int item = it * 512 + tid;
        int pr = item & 127, rr = item >> 7;
        int p = p0 + pr;
        int ob = 2 + rr * 3;
        const unsigned short* sp = slab + pr * SLAB_STR + ob;
        float l0 = bfu(sp[0]) + bc_s[ob + 0];
        float l1 = bfu(sp[1]) + bc_s[ob + 1];
        float l2 = bfu(sp[2]) + bc_s[ob + 2];
        float mx = fmaxf(l0, fmaxf(l1, l2));
        float e0 = __expf(l0 - mx), e1 = __expf(l1 - mx), e2 = __expf(l2 - mx);
        float inv = __fdividef(1.0f, e0 + e1 + e2);
        size_t base = (rr < 24)
            ? (size_t)OFF_H2H + ((size_t)(b * 24 + rr) * NPAIR + p) * 3
            : (size_t)OFF_T2T + ((size_t)(b * 24 + rr - 24) * NPAIR + p) * 3;
        __builtin_nontemporal_store(e0 * inv, &out[base + 0]);
        __builtin_nontemporal_store(e1 * inv, &out[base + 1]);
        __builtin_nontemporal_store(e2 * inv, &out[base + 2]);
    }
}

extern "C" void kernel_launch(void* const* d_in, const int* in_sizes, int n_in,
                              void* d_out, int out_size, void* d_ws, size_t ws_size,
                              hipStream_t stream) {
    const float* hidden = (const float*)d_in[0];
    const float* fc_w   = (const float*)d_in[1];
    const float* fc_b   = (const float*)d_in[2];
    const float* h2t_w  = (const float*)d_in[3];
    const float* h2t_b  = (const float*)d_in[4];
    const float* h2h_w  = (const float*)d_in[5];
    const float* h2h_b  = (const float*)d_in[6];
    const float* t2t_w  = (const float*)d_in[7];
    const float* t2t_b  = (const float*)d_in[8];

    char* wsb = (char*)d_ws;
    unsigned short* LBw  = (unsigned short*)(wsb);              // 1024*768 bf16 = 1.5 MB
    unsigned short* RBw  = (unsigned short*)(wsb + 1572864);    // 1.5 MB
    unsigned short* Bpk  = (unsigned short*)(wsb + 3145728);    // 12*24576 B = 288 KB (padded chunks)
    unsigned short* fcwb = (unsigned short*)(wsb + 3440640);    // 2.25 MB
    float*          bc   = (float*)        (wsb + 5799936);     // 640 B

    float* out = (float*)d_out;

    pack_kernel<<<(N_BPK + N_FCW + NOUTP + 255) / 256, 256, 0, stream>>>(
        h2t_w, h2h_w, t2t_w, h2t_b, h2h_b, t2t_b, fc_w, Bpk, fcwb, bc);
    lr_mfma<<<dim3(16, 24), 256, 0, stream>>>(hidden, fcwb, fc_b, LBw, RBw);
    pair_mfma<<<NTOT / 128, 512, 0, stream>>>(LBw, RBw, Bpk, bc, out);
}

// Round 12
// 95.749 us; speedup vs baseline: 1.0334x; 1.0334x over previous
//
#include <hip/hip_runtime.h>
#include <hip/hip_bf16.h>

#define H 768
#define SEQ 256
#define NPAIR 32896                // S*(S+1)/2 = 128*257
#define NTOT 131584                // 4*NPAIR = 1028*128
#define NOUTP 160
#define OFF_H2H 263168u            // 4*32896*2
#define OFF_T2T 9737216u           // OFF_H2H + 4*24*32896*3

#define N_BPK 122880               // 12 chunks * 20 frags * 64 lanes * 8 bf16 (real slots)
#define SCL 2.8853900817779268f    // 2*log2(e): pre-scale L/R so stage tanh needs no mul

#define CH 64                      // k-elems per chunk
#define NCH 12
#define BSLOT 24576                // padded B chunk bytes (real 20480)
#define SLAB_STR 166               // bf16 slab stride (83 words, odd -> conflict-free)

typedef short bf16x8 __attribute__((ext_vector_type(8)));
typedef float f32x4 __attribute__((ext_vector_type(4)));
typedef float f32x16 __attribute__((ext_vector_type(16)));

__device__ __forceinline__ float tanh_s(float xs) {
    // xs = 2*log2(e)*x  ->  tanh(x) = 1 - 2/(exp2(xs)+1)
    float e = __builtin_amdgcn_exp2f(xs);
    return fmaf(-2.0f, __builtin_amdgcn_rcpf(e + 1.0f), 1.0f);
}
__device__ __forceinline__ float bf_lo(int w){ return __uint_as_float(((unsigned)w) << 16); }
__device__ __forceinline__ float bf_hi(int w){ return __uint_as_float(((unsigned)w) & 0xffff0000u); }
__device__ __forceinline__ float bfu(unsigned short u){ return __uint_as_float(((unsigned)u) << 16); }
__device__ __forceinline__ int cvtpk(float lo, float hi) {
    int r;
    asm("v_cvt_pk_bf16_f32 %0, %1, %2" : "=v"(r) : "v"(lo), "v"(hi));
    return r;
}
__device__ __forceinline__ unsigned short bf16r(float x){
    unsigned int u = __float_as_uint(x);
    u += 0x7fffu + ((u >> 16) & 1u);
    return (unsigned short)(u >> 16);
}
__device__ __forceinline__ bf16x8 tanh_frag(int4 lv, int4 rv) {
    int4 st;
    st.x = cvtpk(tanh_s(bf_lo(lv.x) + bf_lo(rv.x)), tanh_s(bf_hi(lv.x) + bf_hi(rv.x)));
    st.y = cvtpk(tanh_s(bf_lo(lv.y) + bf_lo(rv.y)), tanh_s(bf_hi(lv.y) + bf_hi(rv.y)));
    st.z = cvtpk(tanh_s(bf_lo(lv.z) + bf_lo(rv.z)), tanh_s(bf_hi(lv.z) + bf_hi(rv.z)));
    st.w = cvtpk(tanh_s(bf_lo(lv.w) + bf_lo(rv.w)), tanh_s(bf_hi(lv.w) + bf_hi(rv.w)));
    return __builtin_bit_cast(bf16x8, st);
}

typedef const __attribute__((address_space(1))) unsigned int* as1_u32p;
typedef __attribute__((address_space(3))) unsigned int* as3_u32p;
__device__ __forceinline__ void gload_lds16(const void* g, void* l) {
    __builtin_amdgcn_global_load_lds((as1_u32p)g, (as3_u32p)l, 16, 0, 0);
}

__device__ __forceinline__ int row_start(int i) { return i * SEQ - (i * (i - 1)) / 2; }
__device__ __forceinline__ void pair_ij(int p, int& oi, int& oj) {
    double disc = 263169.0 - 8.0 * (double)p;   // (2S+1)^2 - 8p
    int i = (int)((513.0 - sqrt(disc)) * 0.5);
    if (i > 0 && row_start(i) > p) --i;
    while (row_start(i + 1) <= p) ++i;
    oi = i;
    oj = i + (p - row_start(i));
}
__device__ __forceinline__ int batch_of(int g) {
    return (g >= 3 * NPAIR) ? 3 : (g >= 2 * NPAIR) ? 2 : (g >= NPAIR) ? 1 : 0;
}

// ---------------- kernel 0: pack Bpk (32x32x16 fragment order, 24KB-strided chunks) + bc ----------------
// idx = ((c*20 + s*5 + f)*64 + lane)*8 + j  ->  W[n = f*32 + (lane&31)][k = c*64 + s*16 + (lane>>5)*8 + j]
__global__ __launch_bounds__(256) void pack_kernel(
    const float* __restrict__ h2t_w, const float* __restrict__ h2h_w,
    const float* __restrict__ t2t_w, const float* __restrict__ h2t_b,
    const float* __restrict__ h2h_b, const float* __restrict__ t2t_b,
    unsigned short* __restrict__ Bpk, float* __restrict__ bc)
{
    int idx = blockIdx.x * 256 + threadIdx.x;
    if (idx < N_BPK) {
        int j = idx & 7, lane = (idx >> 3) & 63, rest = idx >> 9;
        int fr = rest % 20, c = rest / 20;
        int s = fr / 5, f = fr % 5;
        int n = f * 32 + (lane & 31);
        int k = c * CH + s * 16 + ((lane >> 5) << 3) + j;
        float v = 0.f;
        if (n < 2)        v = h2t_w[n * H + k];
        else if (n < 74)  v = h2h_w[(n - 2) * H + k];
        else if (n < 146) v = t2t_w[(n - 74) * H + k];
        Bpk[c * 12288 + (idx - c * 10240)] = bf16r(v);   // 12288 shorts = 24576 B stride
    } else if (idx < N_BPK + NOUTP) {
        int q = idx - N_BPK;
        float v = 0.f;
        if (q < 2)        v = h2t_b[q];
        else if (q < 74)  v = h2h_b[q - 2];
        else if (q < 146) v = t2t_b[q - 74];
        bc[q] = v;
    }
}

// ---------------- kernel 1: LB/RB = hidden @ fc_w (bf16 MFMA, reads fc_w f32 directly), pre-scaled ----------------
__global__ __launch_bounds__(256, 2) void lr_mfma(
    const float* __restrict__ hidden, const float* __restrict__ fc_w,
    const float* __restrict__ fc_b,
    unsigned short* __restrict__ LB, unsigned short* __restrict__ RB)
{
    __shared__ __align__(16) char sm[16384];          // A 8KB | B 8KB
    const int tid = threadIdx.x, l = tid & 63, w = tid >> 6;
    const int wm = w >> 1, wn = w & 1;
    const int m0 = blockIdx.x * 64, n0 = blockIdx.y * 64;
    f32x4 acc[2][2] = {};
    for (int c = 0; c < 12; ++c) {
        const int k0 = c * 64;
        #pragma unroll
        for (int it = 0; it < 2; ++it) {              // A: 64 rows x 64 k, cvt f32->bf16
            int idx = tid + it * 256;
            int row = idx >> 3, k8 = idx & 7;
            const float4* src = reinterpret_cast<const float4*>(hidden + (size_t)(m0 + row) * H + k0 + k8 * 8);
            float4 a = src[0], bq = src[1];
            int4 st;
            st.x = cvtpk(a.x, a.y);  st.y = cvtpk(a.z, a.w);
            st.z = cvtpk(bq.x, bq.y); st.w = cvtpk(bq.z, bq.w);
            *reinterpret_cast<int4*>(sm + row * 128 + ((k8 * 16) ^ ((row & 7) << 4))) = st;
        }
        #pragma unroll
        for (int it = 0; it < 2; ++it) {              // B: 64 rows x 64 k from fc_w (f32 -> bf16)
            int idx = tid + it * 256;
            int row = idx >> 3, k8 = idx & 7;
            const float* fsrc = (n0 < H)
                ? fc_w + (size_t)(n0 + row) * (2 * H) + k0 + k8 * 8
                : fc_w + (size_t)(n0 - H + row) * (2 * H) + H + k0 + k8 * 8;
            const float4* src = reinterpret_cast<const float4*>(fsrc);
            float4 a = src[0], bq = src[1];
            int4 st;
            st.x = cvtpk(a.x, a.y);  st.y = cvtpk(a.z, a.w);
            st.z = cvtpk(bq.x, bq.y); st.w = cvtpk(bq.z, bq.w);
            *reinterpret_cast<int4*>(sm + 8192 + row * 128 + ((k8 * 16) ^ ((row & 7) << 4))) = st;
        }
        __syncthreads();
        #pragma unroll
        for (int kk = 0; kk < 2; ++kk) {
            const int sl = kk * 4 + (l >> 4);
            const int swz = (l & 7) << 4;
            bf16x8 af[2], bfr[2];
            #pragma unroll
            for (int a = 0; a < 2; ++a) {
                int row = 32 * wm + 16 * a + (l & 15);
                af[a] = *reinterpret_cast<const bf16x8*>(sm + row * 128 + ((sl * 16) ^ swz));
            }
            #pragma unroll
            for (int f = 0; f < 2; ++f) {
                int row = 32 * wn + 16 * f + (l & 15);
                bfr[f] = *reinterpret_cast<const bf16x8*>(sm + 8192 + row * 128 + ((sl * 16) ^ swz));
            }
            #pragma unroll
            for (int a = 0; a < 2; ++a)
                #pragma unroll
                for (int f = 0; f < 2; ++f)
                    acc[a][f] = __builtin_amdgcn_mfma_f32_16x16x32_bf16(af[a], bfr[f], acc[a][f], 0, 0, 0);
        }
        __syncthreads();
    }
    #pragma unroll
    for (int a = 0; a < 2; ++a)
        #pragma unroll
        for (int f = 0; f < 2; ++f)
            #pragma unroll
            for (int r = 0; r < 4; ++r) {
                int row = m0 + 32 * wm + 16 * a + 4 * (l >> 4) + r;
                int col = n0 + 32 * wn + 16 * f + (l & 15);
                float v = acc[a][f][r];
                if (n0 < H) LB[(size_t)row * H + col] = bf16r((v + fc_b[col]) * SCL);
                else        RB[(size_t)row * H + (col - H)] = bf16r(v * SCL);
            }
}

// ---------------- kernel 2: 32x32x16 pair kernel — B ds_reads halved ----------------
// block = 256 thr (4 waves x 32 rows), wave cols = 160 (acc 5 x f32x16 = 80 regs), M-tile = 128,
// grid = 1028 (exact, no batch straddle). A: 4 tanh frags/thread/chunk straight into registers.
// B: 5 uniform gload_lds/thread into 24KB dbuf half; counted vmcnt(8) barrier keeps 8 LR in flight.
__global__ __launch_bounds__(256) void pair_mfma(
    const unsigned short* __restrict__ LB, const unsigned short* __restrict__ RB,
    const unsigned short* __restrict__ Bpk, const float* __restrict__ bc,
    float* __restrict__ out)
{
    __shared__ __align__(16) char sm[49792];
    // K-loop: B buf0 [0,24576) | buf1 [24576,49152)
    // epilogue: bf16 slab [128][166] = 42496 B at [0,42496)
    // bc_s [49152,49792) lives throughout
    float* bc_s = reinterpret_cast<float*>(sm + 49152);

    const int tid = threadIdx.x, l = tid & 63, w = tid >> 6;
    const int g0 = blockIdx.x * 128;                 // NPAIR % 128 == 0 -> no batch straddle
    const int b = batch_of(g0);
    const int p0 = g0 - b * NPAIR;

    if (tid < NOUTP) bc_s[tid] = bc[tid];

    // per-thread pair decode: wave w owns rows 32w..32w+31; thread row = 32w + (l&31)
    const int row = 32 * w + (l & 31);
    int pi, pj;
    pair_ij(p0 + row, pi, pj);
    const int kb = (l >> 5) << 3;                    // lane k-phase base (bf16 elems): 0 or 8
    const unsigned short* lp = LB + (size_t)(b * SEQ + pi) * H + kb;
    const unsigned short* rp = RB + (size_t)(b * SEQ + pj) * H + kb;

    // B staging: 5 uniform rounds of 4 KB (256 thr x 16 B); per-lane src, wave-uniform dest
    const char* bpk = reinterpret_cast<const char*>(Bpk);
    const int soff = w * 1024 + l * 16;
    const int doff = w * 1024;

    f32x16 acc[5] = {};

    {   // prologue: B(0) -> buf0 ; LR(0) -> regs
        #pragma unroll
        for (int r = 0; r < 5; ++r)
            gload_lds16(bpk + r * 4096 + soff, sm + r * 4096 + doff);
        __builtin_amdgcn_sched_barrier(0);
    }
    int4 lv0 = *reinterpret_cast<const int4*>(lp);
    int4 lv1 = *reinterpret_cast<const int4*>(lp + 16);
    int4 lv2 = *reinterpret_cast<const int4*>(lp + 32);
    int4 lv3 = *reinterpret_cast<const int4*>(lp + 48);
    int4 rv0 = *reinterpret_cast<const int4*>(rp);
    int4 rv1 = *reinterpret_cast<const int4*>(rp + 16);
    int4 rv2 = *reinterpret_cast<const int4*>(rp + 32);
    int4 rv3 = *reinterpret_cast<const int4*>(rp + 48);
    asm volatile("s_waitcnt vmcnt(8) lgkmcnt(0)" ::: "memory");   // drain B(0); keep 8 LR in flight
    __builtin_amdgcn_s_barrier();
    __builtin_amdgcn_sched_barrier(0);

    #pragma unroll 2
    for (int c = 0; c < NCH - 1; ++c) {
        char* bufn = sm + (((c + 1) & 1) ? BSLOT : 0);
        const char* bn = bpk + (c + 1) * BSLOT;
        // phase 1: B(c+1) -> bufn (oldest outstanding after prior drain)
        #pragma unroll
        for (int r = 0; r < 5; ++r)
            gload_lds16(bn + r * 4096 + soff, bufn + r * 4096 + doff);
        __builtin_amdgcn_sched_barrier(0);
        // phase 2: tanh chunk c -> 4 A-frags (auto-vmcnt drains only the 8 LR, keeps B)
        bf16x8 a0 = tanh_frag(lv0, rv0);
        bf16x8 a1 = tanh_frag(lv1, rv1);
        bf16x8 a2 = tanh_frag(lv2, rv2);
        bf16x8 a3 = tanh_frag(lv3, rv3);
        // phase 3: issue LR(c+1) (newest: survive this chunk's counted barrier)
        const int co = (c + 1) * CH;
        lv0 = *reinterpret_cast<const int4*>(lp + co);
        lv1 = *reinterpret_cast<const int4*>(lp + co + 16);
        lv2 = *reinterpret_cast<const int4*>(lp + co + 32);
        lv3 = *reinterpret_cast<const int4*>(lp + co + 48);
        rv0 = *reinterpret_cast<const int4*>(rp + co);
        rv1 = *reinterpret_cast<const int4*>(rp + co + 16);
        rv2 = *reinterpret_cast<const int4*>(rp + co + 32);
        rv3 = *reinterpret_cast<const int4*>(rp + co + 48);
        // phase 4: 20 x {ds_read_b128 + 32x32x16 MFMA} on bufc (each read feeds 32 rows)
        const char* bufc = sm + ((c & 1) ? BSLOT : 0);
        #pragma unroll
        for (int f = 0; f < 5; ++f) {
            bf16x8 bfr = *reinterpret_cast<const bf16x8*>(bufc + ((0 * 5 + f) * 64 + l) * 16);
            acc[f] = __builtin_amdgcn_mfma_f32_32x32x16_bf16(a0, bfr, acc[f], 0, 0, 0);
        }
        #pragma unroll
        for (int f = 0; f < 5; ++f) {
            bf16x8 bfr = *reinterpret_cast<const bf16x8*>(bufc + ((1 * 5 + f) * 64 + l) * 16);
            acc[f] = __builtin_amdgcn_mfma_f32_32x32x16_bf16(a1, bfr, acc[f], 0, 0, 0);
        }
        #pragma unroll
        for (int f = 0; f < 5; ++f) {
            bf16x8 bfr = *reinterpret_cast<const bf16x8*>(bufc + ((2 * 5 + f) * 64 + l) * 16);
            acc[f] = __builtin_amdgcn_mfma_f32_32x32x16_bf16(a2, bfr, acc[f], 0, 0, 0);
        }
        #pragma unroll
        for (int f = 0; f < 5; ++f) {
            bf16x8 bfr = *reinterpret_cast<const bf16x8*>(bufc + ((3 * 5 + f) * 64 + l) * 16);
            acc[f] = __builtin_amdgcn_mfma_f32_32x32x16_bf16(a3, bfr, acc[f], 0, 0, 0);
        }
        // phase 5: counted barrier — drain B(c+1) (5), keep the 8 LR(c+1) in flight
        asm volatile("s_waitcnt vmcnt(8) lgkmcnt(0)" ::: "memory");
        __builtin_amdgcn_s_barrier();
        __builtin_amdgcn_sched_barrier(0);
    }
    {   // peeled chunk 11 (no prefetch); buf1 (11 odd)
        bf16x8 a0 = tanh_frag(lv0, rv0);
        bf16x8 a1 = tanh_frag(lv1, rv1);
        bf16x8 a2 = tanh_frag(lv2, rv2);
        bf16x8 a3 = tanh_frag(lv3, rv3);
        const char* bufc = sm + BSLOT;
        #pragma unroll
        for (int f = 0; f < 5; ++f) {
            bf16x8 bfr = *reinterpret_cast<const bf16x8*>(bufc + ((0 * 5 + f) * 64 + l) * 16);
            acc[f] = __builtin_amdgcn_mfma_f32_32x32x16_bf16(a0, bfr, acc[f], 0, 0, 0);
        }
        #pragma unroll
        for (int f = 0; f < 5; ++f) {
            bf16x8 bfr = *reinterpret_cast<const bf16x8*>(bufc + ((1 * 5 + f) * 64 + l) * 16);
            acc[f] = __builtin_amdgcn_mfma_f32_32x32x16_bf16(a1, bfr, acc[f], 0, 0, 0);
        }
        #pragma unroll
        for (int f = 0; f < 5; ++f) {
            bf16x8 bfr = *reinterpret_cast<const bf16x8*>(bufc + ((2 * 5 + f) * 64 + l) * 16);
            acc[f] = __builtin_amdgcn_mfma_f32_32x32x16_bf16(a2, bfr, acc[f], 0, 0, 0);
        }
        #pragma unroll
        for (int f = 0; f < 5; ++f) {
            bf16x8 bfr = *reinterpret_cast<const bf16x8*>(bufc + ((3 * 5 + f) * 64 + l) * 16);
            acc[f] = __builtin_amdgcn_mfma_f32_32x32x16_bf16(a3, bfr, acc[f], 0, 0, 0);
        }
    }
    asm volatile("s_waitcnt lgkmcnt(0)" ::: "memory");   // all LDS reads retired before slab aliases
    __builtin_amdgcn_s_barrier();

    // epilogue: 4 waves dump 128 rows -> slab, one barrier, parallel softmax
    // C layout (32x32): col = lane&31, row = (reg&3) + 8*(reg>>2) + 4*(lane>>5)
    unsigned short* slab = reinterpret_cast<unsigned short*>(sm);
    #pragma unroll
    for (int f = 0; f < 5; ++f)
        #pragma unroll
        for (int g = 0; g < 16; ++g) {
            int rw = 32 * w + (g & 3) + 8 * (g >> 2) + 4 * (l >> 5);
            slab[rw * SLAB_STR + f * 32 + (l & 31)] = bf16r(acc[f][g]);
        }
    __syncthreads();

    {                                                // h2t: 128 rows x 2 (flat out idx = 2g+tt)
        int pr = tid >> 1, tt = tid & 1;
        float val = bfu(slab[pr * SLAB_STR + tt]) + bc_s[tt];
        __builtin_nontemporal_store(val, &out[(size_t)(g0 + pr) * 2 + tt]);
    }
    #pragma unroll
    for (int it = 0; it < 24; ++it) {                // 48 rr x 128 rows, rr-major (coalesced stores)
        int item = it * 256 + tid;
        int pr = item & 127, rr = item >> 7;
        int p = p0 + pr;
        int ob = 2 + rr * 3;
        const unsigned short* sp = slab + pr * SLAB_STR + ob;
        float l0 = bfu(sp[0]) + bc_s[ob + 0];
        float l1 = bfu(sp[1]) + bc_s[ob + 1];
        float l2 = bfu(sp[2]) + bc_s[ob + 2];
        float mx = fmaxf(l0, fmaxf(l1, l2));
        float e0 = __expf(l0 - mx), e1 = __expf(l1 - mx), e2 = __expf(l2 - mx);
        float inv = __fdividef(1.0f, e0 + e1 + e2);
        size_t base = (rr < 24)
            ? (size_t)OFF_H2H + ((size_t)(b * 24 + rr) * NPAIR + p) * 3
            : (size_t)OFF_T2T + ((size_t)(b * 24 + rr - 24) * NPAIR + p) * 3;
        __builtin_nontemporal_store(e0 * inv, &out[base + 0]);
        __builtin_nontemporal_store(e1 * inv, &out[base + 1]);
        __builtin_nontemporal_store(e2 * inv, &out[base + 2]);
    }
}

extern "C" void kernel_launch(void* const* d_in, const int* in_sizes, int n_in,
                              void* d_out, int out_size, void* d_ws, size_t ws_size,
                              hipStream_t stream) {
    const float* hidden = (const float*)d_in[0];
    const float* fc_w   = (const float*)d_in[1];
    const float* fc_b   = (const float*)d_in[2];
    const float* h2t_w  = (const float*)d_in[3];
    const float* h2t_b  = (const float*)d_in[4];
    const float* h2h_w  = (const float*)d_in[5];
    const float* h2h_b  = (const float*)d_in[6];
    const float* t2t_w  = (const float*)d_in[7];
    const float* t2t_b  = (const float*)d_in[8];

    char* wsb = (char*)d_ws;
    unsigned short* LBw  = (unsigned short*)(wsb);              // 1024*768 bf16 = 1.5 MB
    unsigned short* RBw  = (unsigned short*)(wsb + 1572864);    // 1.5 MB
    unsigned short* Bpk  = (unsigned short*)(wsb + 3145728);    // 12*24576 B = 288 KB (padded chunks)
    float*          bc   = (float*)        (wsb + 3440640);     // 640 B

    float* out = (float*)d_out;

    pack_kernel<<<(N_BPK + NOUTP + 255) / 256, 256, 0, stream>>>(
        h2t_w, h2h_w, t2t_w, h2t_b, h2h_b, t2t_b, Bpk, bc);
    lr_mfma<<<dim3(16, 24), 256, 0, stream>>>(hidden, fc_w, fc_b, LBw, RBw);
    pair_mfma<<<NTOT / 128, 256, 0, stream>>>(LBw, RBw, Bpk, bc, out);
}